// Round 1
// baseline (119.060 us; speedup 1.0000x reference)
//
#include <hip/hip_runtime.h>
#include <hip/hip_bf16.h>
#include <string.h>

// GlobalSpatialAttention: B=8, C=128, N=4096, E=64, fp32 in/out, bf16 MFMA inside.
// ws layout (total ~48.7 MB):
//   WF    24576 sh  packed qkv weight frags   [mt6][kg8][l64][t8]
//   WattF  8192 sh  packed w_att frags        [mt4][kg4][l64][t8]
//   Qf/Kf  4MB each [b][jt128][kg4][l64][t8]  elem M[e][pos], e=16kg+4(l>>5)+(t&3)+8(t>>2), pos=32jt+(l&31)
//   Vf     4MB      [b][et2][ig256][l64][t8]  elem V[e][i],  e=32et+(l&31), i=16ig+4(l>>5)+(t&3)+8(t>>2)
//   sumsP  512KB f32 [b][i][jc4] ; invl 128KB f32 [b][i]
//   fgsP   32MB f32 [ic4][b][jt][kg][l][t] ; fgsF 4MB bf16 [b][jt][kg][l][t]

#define LOG2E 1.4426950408889634f

typedef short bfrag __attribute__((ext_vector_type(8)));    // 8 bf16 in 4 VGPRs
typedef float f32x16 __attribute__((ext_vector_type(16)));

#define MFMA(a, b, c) __builtin_amdgcn_mfma_f32_32x32x16_bf16(a, b, c, 0, 0, 0)

__device__ __forceinline__ short f2bf(float f) {
  __hip_bfloat16 h = __float2bfloat16(f);
  short s;
  __builtin_memcpy(&s, &h, 2);
  return s;
}
__device__ __forceinline__ float bf2f(short s) {
  unsigned u = ((unsigned)(unsigned short)s) << 16;
  float f;
  __builtin_memcpy(&f, &u, 4);
  return f;
}
__device__ __forceinline__ f32x16 zero16() {
  f32x16 z;
#pragma unroll
  for (int r = 0; r < 16; ++r) z[r] = 0.f;
  return z;
}

// ---------------- K_pre: pack weights into fragment-ready bf16 ----------------
__global__ void k_pack(const float* __restrict__ wq, const float* __restrict__ wk,
                       const float* __restrict__ wv, const float* __restrict__ watt,
                       short* __restrict__ WF, short* __restrict__ WattF) {
  int idx = blockIdx.x * 256 + threadIdx.x;  // 32768 total
  if (idx < 24576) {
    int t = idx & 7, l = (idx >> 3) & 63, kg = (idx >> 9) & 7, mt = idx >> 12;
    int e = mt * 32 + (l & 31);
    int c = 16 * kg + 4 * (l >> 5) + (t & 3) + 8 * (t >> 2);
    const float* src = (e < 64) ? wq : ((e < 128) ? wk : wv);
    WF[idx] = f2bf(src[(e & 63) * 128 + c]);
  } else {
    int i2 = idx - 24576;  // 8192
    int t = i2 & 7, l = (i2 >> 3) & 63, kg = (i2 >> 9) & 3, mt = i2 >> 11;
    int cr = mt * 32 + (l & 31);
    int e = 16 * kg + 4 * (l >> 5) + (t & 3) + 8 * (t >> 2);
    WattF[i2] = f2bf(watt[cr * 64 + e]);
  }
}

// ---------------- K0: QKV projection, writes frag-ready Qf/Kf/Vf ----------------
__global__ __launch_bounds__(256) void k_qkv(
    const float* __restrict__ feat, const short* __restrict__ WF,
    const float* __restrict__ bq, const float* __restrict__ bk, const float* __restrict__ bv,
    short* __restrict__ Qf, short* __restrict__ Kf, short* __restrict__ Vf) {
  __shared__ short xf[16384];  // x frags: [tt4][kg8][l64][t8]
  int jb = blockIdx.x, b = blockIdx.y;
  int tid = threadIdx.x;
  int p0 = jb * 128;
  for (int idx = tid; idx < 16384; idx += 256) {
    int c = idx >> 7, pl = idx & 127;
    float v = feat[((b * 128 + c) << 12) + p0 + pl];
    int tt = pl >> 5, pn = pl & 31;
    int kg = c >> 4, cw = c & 15;
    int l = pn + 32 * ((cw >> 2) & 1);
    int t = (cw & 3) + 4 * (cw >> 3);
    xf[((tt * 8 + kg) * 64 + l) * 8 + t] = f2bf(v);
  }
  __syncthreads();
  int w = tid >> 6, lane = tid & 63;
  int jt = jb * 4 + w;
  bfrag xr[8];
#pragma unroll
  for (int kg = 0; kg < 8; ++kg)
    xr[kg] = *(const bfrag*)&xf[((w * 8 + kg) * 64 + lane) * 8];
  int el[16];
#pragma unroll
  for (int r = 0; r < 16; ++r) el[r] = (r & 3) + 8 * (r >> 2) + 4 * (lane >> 5);

#pragma unroll
  for (int mt = 0; mt < 6; ++mt) {
    f32x16 acc = zero16();
#pragma unroll
    for (int kg = 0; kg < 8; ++kg) {
      bfrag wf = *(const bfrag*)&WF[((mt * 8 + kg) * 64 + lane) * 8];
      if (mt < 4) acc = MFMA(wf, xr[kg], acc);   // D[e][p]
      else        acc = MFMA(xr[kg], wf, acc);   // D[p][e]  (V transposed)
    }
    bfrag o0, o1;
    if (mt < 2) {  // Q
#pragma unroll
      for (int r = 0; r < 8; ++r) {
        o0[r] = f2bf(acc[r] + bq[mt * 32 + el[r]]);
        o1[r] = f2bf(acc[r + 8] + bq[mt * 32 + el[r + 8]]);
      }
      short* base = Qf + (((b * 128 + jt) * 4 + 2 * mt) * 64 + lane) * 8;
      *(bfrag*)base = o0;
      *(bfrag*)(base + 512) = o1;
    } else if (mt < 4) {  // K, folded *log2e for exp2 softmax
#pragma unroll
      for (int r = 0; r < 8; ++r) {
        o0[r] = f2bf((acc[r] + bk[(mt - 2) * 32 + el[r]]) * LOG2E);
        o1[r] = f2bf((acc[r + 8] + bk[(mt - 2) * 32 + el[r + 8]]) * LOG2E);
      }
      short* base = Kf + (((b * 128 + jt) * 4 + 2 * (mt - 2)) * 64 + lane) * 8;
      *(bfrag*)base = o0;
      *(bfrag*)(base + 512) = o1;
    } else {  // V (rows=p, cols=e)
      float bias = bv[(mt - 4) * 32 + (lane & 31)];
#pragma unroll
      for (int r = 0; r < 8; ++r) {
        o0[r] = f2bf(acc[r] + bias);
        o1[r] = f2bf(acc[r + 8] + bias);
      }
      short* base = Vf + (((b * 2 + (mt - 4)) * 256 + 2 * jt) * 64 + lane) * 8;
      *(bfrag*)base = o0;
      *(bfrag*)(base + 512) = o1;
    }
  }
}

// ---------------- K1: row sums l_i = sum_j exp(S[i,j]) (partial over j-chunk) ----------------
__global__ __launch_bounds__(256) void k_pass1(
    const short* __restrict__ Kf, const short* __restrict__ Qf,
    float* __restrict__ sumsP) {
  __shared__ int4 ldsQ[256];  // 4KB: one Q j-tile [kg4][l64] of 16B
  int ib = blockIdx.x, b = blockIdx.y, jc = blockIdx.z;
  int tid = threadIdx.x, w = tid >> 6, lane = tid & 63;
  int it = ib * 4 + w;
  bfrag kf[4];
#pragma unroll
  for (int kg = 0; kg < 4; ++kg)
    kf[kg] = *(const bfrag*)&Kf[(((b * 128 + it) * 4 + kg) * 64 + lane) * 8];
  float part[16];
#pragma unroll
  for (int r = 0; r < 16; ++r) part[r] = 0.f;

  for (int s = 0; s < 32; ++s) {
    int jt = jc * 32 + s;
    const int4* qsrc = (const int4*)(Qf + (size_t)(b * 128 + jt) * 2048);
    int4 v = qsrc[tid];
    __syncthreads();
    ldsQ[tid] = v;
    __syncthreads();
    f32x16 acc = zero16();
#pragma unroll
    for (int kg = 0; kg < 4; ++kg) {
      bfrag qf = *(const bfrag*)&ldsQ[kg * 64 + lane];
      acc = MFMA(kf[kg], qf, acc);
    }
#pragma unroll
    for (int r = 0; r < 16; ++r) part[r] += __builtin_amdgcn_exp2f(acc[r]);
  }
#pragma unroll
  for (int r = 0; r < 16; ++r) {
    float v = part[r];
#pragma unroll
    for (int m = 1; m < 32; m <<= 1) v += __shfl_xor(v, m, 64);
    part[r] = v;
  }
  if ((lane & 31) == 0) {
    int h = lane >> 5;
#pragma unroll
    for (int r = 0; r < 16; ++r) {
      int i = it * 32 + (r & 3) + 8 * (r >> 2) + 4 * h;
      sumsP[(b * 4096 + i) * 4 + jc] = part[r];
    }
  }
}

// ---------------- K1b: invl = 1/sum(4 partials) ----------------
__global__ void k_finl(const float* __restrict__ sumsP, float* __restrict__ invl) {
  int idx = blockIdx.x * 256 + threadIdx.x;  // 32768
  const float* s = sumsP + (size_t)idx * 4;
  invl[idx] = 1.0f / (s[0] + s[1] + s[2] + s[3]);
}

// ---------------- K1c: Vf *= invl[i]  (in place; Vf rewritten each call by k_qkv) ----------------
__global__ void k_scalev(short* __restrict__ Vf, const float* __restrict__ invl) {
  int lin = blockIdx.x * 256 + threadIdx.x;  // 262144
  int l = lin & 63, ig = (lin >> 6) & 255, b = lin >> 15;
  short* p = Vf + (size_t)lin * 8;
  bfrag v = *(const bfrag*)p;
  bfrag o;
#pragma unroll
  for (int t = 0; t < 8; ++t) {
    int i = 16 * ig + 4 * (l >> 5) + (t & 3) + 8 * (t >> 2);
    o[t] = f2bf(bf2f(v[t]) * invl[b * 4096 + i]);
  }
  *(bfrag*)p = o;
}

// ---------------- K2: fgs[e,j] = sum_i V'[e,i] * exp(S[i,j]) (partial over i-chunk) ----------------
__global__ __launch_bounds__(256) void k_pass2(
    const short* __restrict__ Qf, const short* __restrict__ Kf, const short* __restrict__ Vf,
    float* __restrict__ fgsP) {
  __shared__ int4 ldsKV[512];  // 8KB: Kf tile (4KB) + Vf tile (4KB)
  int jb = blockIdx.x, b = blockIdx.y, ic = blockIdx.z;
  int tid = threadIdx.x, w = tid >> 6, lane = tid & 63;
  int jt = jb * 4 + w;
  bfrag qf[4];
#pragma unroll
  for (int kg = 0; kg < 4; ++kg)
    qf[kg] = *(const bfrag*)&Qf[(((b * 128 + jt) * 4 + kg) * 64 + lane) * 8];
  f32x16 f0 = zero16(), f1 = zero16();

  for (int s = 0; s < 32; ++s) {
    int it = ic * 32 + s;
    const int4* ksrc = (const int4*)(Kf + (size_t)(b * 128 + it) * 2048);
    int4 r0 = ksrc[tid];
    const int4* vsrc0 = (const int4*)(Vf + ((size_t)(b * 2 + 0) * 256 + 2 * it) * 512);
    const int4* vsrc1 = (const int4*)(Vf + ((size_t)(b * 2 + 1) * 256 + 2 * it) * 512);
    int4 r1 = (tid < 128) ? vsrc0[tid] : vsrc1[tid - 128];
    __syncthreads();
    ldsKV[tid] = r0;
    ldsKV[256 + tid] = r1;
    __syncthreads();
    f32x16 sacc = zero16();
#pragma unroll
    for (int kg = 0; kg < 4; ++kg) {
      bfrag kfr = *(const bfrag*)&ldsKV[kg * 64 + lane];
      sacc = MFMA(kfr, qf[kg], sacc);
    }
    bfrag pb0, pb1;  // P frags: regs 0-7 -> i in [0,16), regs 8-15 -> [16,32)
#pragma unroll
    for (int t = 0; t < 8; ++t) {
      pb0[t] = f2bf(__builtin_amdgcn_exp2f(sacc[t]));
      pb1[t] = f2bf(__builtin_amdgcn_exp2f(sacc[t + 8]));
    }
    bfrag v00 = *(const bfrag*)&ldsKV[256 + 0 * 64 + lane];
    bfrag v01 = *(const bfrag*)&ldsKV[256 + 1 * 64 + lane];
    bfrag v10 = *(const bfrag*)&ldsKV[256 + 2 * 64 + lane];
    bfrag v11 = *(const bfrag*)&ldsKV[256 + 3 * 64 + lane];
    f0 = MFMA(v00, pb0, f0);
    f0 = MFMA(v01, pb1, f0);
    f1 = MFMA(v10, pb0, f1);
    f1 = MFMA(v11, pb1, f1);
  }
  size_t obase = ((size_t)(ic * 8 + b) * 128 + jt) * 4;
#pragma unroll
  for (int h = 0; h < 2; ++h) {
    float* d0 = fgsP + ((obase + 0 + h) * 64 + lane) * 8;
    float* d1 = fgsP + ((obase + 2 + h) * 64 + lane) * 8;
#pragma unroll
    for (int t = 0; t < 8; ++t) {
      d0[t] = f0[8 * h + t];
      d1[t] = f1[8 * h + t];
    }
  }
}

// ---------------- K3: combine 4 i-chunk partials, convert to bf16 frags ----------------
__global__ void k_comb(const float* __restrict__ fgsP, short* __restrict__ fgsF) {
  int idx = blockIdx.x * 256 + threadIdx.x;  // 262144
  const float* s = fgsP + (size_t)idx * 8;
  bfrag o;
#pragma unroll
  for (int t = 0; t < 8; ++t) {
    float v = s[t] + s[t + 2097152] + s[t + 2 * 2097152] + s[t + 3 * 2097152];
    o[t] = f2bf(v);
  }
  *(bfrag*)(fgsF + (size_t)idx * 8) = o;
}

// ---------------- K4: out = w_att @ fgs + b_att (fp32 out) ----------------
__global__ __launch_bounds__(256) void k_out(
    const short* __restrict__ fgsF, const short* __restrict__ WattF,
    const float* __restrict__ batt, float* __restrict__ out) {
  int jb = blockIdx.x, b = blockIdx.y;
  int tid = threadIdx.x, w = tid >> 6, lane = tid & 63;
  int jt = jb * 4 + w;
  bfrag gf[4];
#pragma unroll
  for (int kg = 0; kg < 4; ++kg)
    gf[kg] = *(const bfrag*)&fgsF[(((b * 128 + jt) * 4 + kg) * 64 + lane) * 8];
  int n = jt * 32 + (lane & 31);
#pragma unroll
  for (int mt = 0; mt < 4; ++mt) {
    f32x16 acc = zero16();
#pragma unroll
    for (int kg = 0; kg < 4; ++kg) {
      bfrag wf = *(const bfrag*)&WattF[((mt * 4 + kg) * 64 + lane) * 8];
      acc = MFMA(wf, gf[kg], acc);
    }
#pragma unroll
    for (int r = 0; r < 16; ++r) {
      int c = 32 * mt + (r & 3) + 8 * (r >> 2) + 4 * (lane >> 5);
      out[((size_t)(b * 128 + c) << 12) + n] = acc[r] + batt[c];
    }
  }
}

extern "C" void kernel_launch(void* const* d_in, const int* in_sizes, int n_in,
                              void* d_out, int out_size, void* d_ws, size_t ws_size,
                              hipStream_t stream) {
  const float* feat = (const float*)d_in[0];
  const float* wq = (const float*)d_in[1];
  const float* bq = (const float*)d_in[2];
  const float* wk = (const float*)d_in[3];
  const float* bk = (const float*)d_in[4];
  const float* wv = (const float*)d_in[5];
  const float* bv = (const float*)d_in[6];
  const float* watt = (const float*)d_in[7];
  const float* batt = (const float*)d_in[8];
  float* out = (float*)d_out;

  char* ws = (char*)d_ws;
  short* WF = (short*)(ws);
  short* WattF = (short*)(ws + 49152);
  short* Qf = (short*)(ws + 65536);
  short* Kf = (short*)(ws + 65536 + 4194304);
  short* Vf = (short*)(ws + 65536 + 2 * 4194304);
  float* sumsP = (float*)(ws + 65536 + 3 * 4194304);
  float* invl = (float*)(ws + 65536 + 3 * 4194304 + 524288);
  float* fgsP = (float*)(ws + 65536 + 3 * 4194304 + 524288 + 131072);
  short* fgsF = (short*)(ws + 65536 + 3 * 4194304 + 524288 + 131072 + 33554432);
  // total ws needed: 51,052,672 bytes

  hipLaunchKernelGGL(k_pack, dim3(128), dim3(256), 0, stream, wq, wk, wv, watt, WF, WattF);
  hipLaunchKernelGGL(k_qkv, dim3(32, 8), dim3(256), 0, stream, feat, WF, bq, bk, bv, Qf, Kf, Vf);
  hipLaunchKernelGGL(k_pass1, dim3(32, 8, 4), dim3(256), 0, stream, Kf, Qf, sumsP);
  hipLaunchKernelGGL(k_finl, dim3(128), dim3(256), 0, stream, sumsP, invl);
  hipLaunchKernelGGL(k_scalev, dim3(1024), dim3(256), 0, stream, Vf, invl);
  hipLaunchKernelGGL(k_pass2, dim3(32, 8, 4), dim3(256), 0, stream, Qf, Kf, Vf, fgsP);
  hipLaunchKernelGGL(k_comb, dim3(1024), dim3(256), 0, stream, fgsP, fgsF);
  hipLaunchKernelGGL(k_out, dim3(32, 8), dim3(256), 0, stream, fgsF, WattF, batt, out);
}

// Round 2
// 111.913 us; speedup vs baseline: 1.0639x; 1.0639x over previous
//
#include <hip/hip_runtime.h>
#include <hip/hip_bf16.h>
#include <string.h>

// GlobalSpatialAttention: B=8, C=128, N=4096, E=64, fp32 in/out, bf16 MFMA inside.
// ws layout (total ~46.8 MB):
//   WF    24576 sh  packed qkv weight frags   [mt6][kg8][l64][t8]
//   WattF  8192 sh  packed w_att frags        [mt4][kg4][l64][t8]
//   Qf/Kf  4MB each [b][jt128][kg4][l64][t8]  elem M[e][pos], e=16kg+4(l>>5)+(t&3)+8(t>>2), pos=32jt+(l&31)
//   Vf     4MB      [b][et2][ig256][l64][t8]  elem V[e][i],  e=32et+(l&31), i=16ig+4(l>>5)+(t&3)+8(t>>2)
//   sumsP  512KB f32 [b][i][jc4] ; invl 128KB f32 [b][i]
//   fgsP   32MB f32 [ic4][b][jt][kg][l][t]   (k_out sums the 4 ic partials directly)

#define LOG2E 1.4426950408889634f

typedef short bfrag __attribute__((ext_vector_type(8)));    // 8 bf16 in 4 VGPRs
typedef float f32x16 __attribute__((ext_vector_type(16)));

#define MFMA(a, b, c) __builtin_amdgcn_mfma_f32_32x32x16_bf16(a, b, c, 0, 0, 0)

__device__ __forceinline__ short f2bf(float f) {
  __hip_bfloat16 h = __float2bfloat16(f);
  short s;
  __builtin_memcpy(&s, &h, 2);
  return s;
}
__device__ __forceinline__ float bf2f(short s) {
  unsigned u = ((unsigned)(unsigned short)s) << 16;
  float f;
  __builtin_memcpy(&f, &u, 4);
  return f;
}
__device__ __forceinline__ f32x16 zero16() {
  f32x16 z;
#pragma unroll
  for (int r = 0; r < 16; ++r) z[r] = 0.f;
  return z;
}

// ---------------- K_pre: pack weights into fragment-ready bf16 ----------------
__global__ void k_pack(const float* __restrict__ wq, const float* __restrict__ wk,
                       const float* __restrict__ wv, const float* __restrict__ watt,
                       short* __restrict__ WF, short* __restrict__ WattF) {
  int idx = blockIdx.x * 256 + threadIdx.x;  // 32768 total
  if (idx < 24576) {
    int t = idx & 7, l = (idx >> 3) & 63, kg = (idx >> 9) & 7, mt = idx >> 12;
    int e = mt * 32 + (l & 31);
    int c = 16 * kg + 4 * (l >> 5) + (t & 3) + 8 * (t >> 2);
    const float* src = (e < 64) ? wq : ((e < 128) ? wk : wv);
    WF[idx] = f2bf(src[(e & 63) * 128 + c]);
  } else {
    int i2 = idx - 24576;  // 8192
    int t = i2 & 7, l = (i2 >> 3) & 63, kg = (i2 >> 9) & 3, mt = i2 >> 11;
    int cr = mt * 32 + (l & 31);
    int e = 16 * kg + 4 * (l >> 5) + (t & 3) + 8 * (t >> 2);
    WattF[i2] = f2bf(watt[cr * 64 + e]);
  }
}

// ---------------- K0: QKV projection, writes frag-ready Qf/Kf/Vf ----------------
__global__ __launch_bounds__(256) void k_qkv(
    const float* __restrict__ feat, const short* __restrict__ WF,
    const float* __restrict__ bq, const float* __restrict__ bk, const float* __restrict__ bv,
    short* __restrict__ Qf, short* __restrict__ Kf, short* __restrict__ Vf) {
  __shared__ short xf[16384];  // x frags: [tt4][kg8][l64][t8]
  int jb = blockIdx.x, b = blockIdx.y;
  int tid = threadIdx.x;
  int p0 = jb * 128;
  for (int idx = tid; idx < 16384; idx += 256) {
    int c = idx >> 7, pl = idx & 127;
    float v = feat[((b * 128 + c) << 12) + p0 + pl];
    int tt = pl >> 5, pn = pl & 31;
    int kg = c >> 4, cw = c & 15;
    int l = pn + 32 * ((cw >> 2) & 1);
    int t = (cw & 3) + 4 * (cw >> 3);
    xf[((tt * 8 + kg) * 64 + l) * 8 + t] = f2bf(v);
  }
  __syncthreads();
  int w = tid >> 6, lane = tid & 63;
  int jt = jb * 4 + w;
  f32x16 z = zero16();
  bfrag xr[8];
#pragma unroll
  for (int kg = 0; kg < 8; ++kg)
    xr[kg] = *(const bfrag*)&xf[((w * 8 + kg) * 64 + lane) * 8];
  int el[16];
#pragma unroll
  for (int r = 0; r < 16; ++r) el[r] = (r & 3) + 8 * (r >> 2) + 4 * (lane >> 5);

#pragma unroll
  for (int mt = 0; mt < 6; ++mt) {
    bfrag w0 = *(const bfrag*)&WF[((mt * 8 + 0) * 64 + lane) * 8];
    f32x16 acc = (mt < 4) ? MFMA(w0, xr[0], z) : MFMA(xr[0], w0, z);
#pragma unroll
    for (int kg = 1; kg < 8; ++kg) {
      bfrag wf = *(const bfrag*)&WF[((mt * 8 + kg) * 64 + lane) * 8];
      if (mt < 4) acc = MFMA(wf, xr[kg], acc);   // D[e][p]
      else        acc = MFMA(xr[kg], wf, acc);   // D[p][e]  (V transposed)
    }
    bfrag o0, o1;
    if (mt < 2) {  // Q
#pragma unroll
      for (int r = 0; r < 8; ++r) {
        o0[r] = f2bf(acc[r] + bq[mt * 32 + el[r]]);
        o1[r] = f2bf(acc[r + 8] + bq[mt * 32 + el[r + 8]]);
      }
      short* base = Qf + (((b * 128 + jt) * 4 + 2 * mt) * 64 + lane) * 8;
      *(bfrag*)base = o0;
      *(bfrag*)(base + 512) = o1;
    } else if (mt < 4) {  // K, folded *log2e for exp2 softmax
#pragma unroll
      for (int r = 0; r < 8; ++r) {
        o0[r] = f2bf((acc[r] + bk[(mt - 2) * 32 + el[r]]) * LOG2E);
        o1[r] = f2bf((acc[r + 8] + bk[(mt - 2) * 32 + el[r + 8]]) * LOG2E);
      }
      short* base = Kf + (((b * 128 + jt) * 4 + 2 * (mt - 2)) * 64 + lane) * 8;
      *(bfrag*)base = o0;
      *(bfrag*)(base + 512) = o1;
    } else {  // V (rows=p, cols=e)
      float bias = bv[(mt - 4) * 32 + (lane & 31)];
#pragma unroll
      for (int r = 0; r < 8; ++r) {
        o0[r] = f2bf(acc[r] + bias);
        o1[r] = f2bf(acc[r + 8] + bias);
      }
      short* base = Vf + (((b * 2 + (mt - 4)) * 256 + 2 * jt) * 64 + lane) * 8;
      *(bfrag*)base = o0;
      *(bfrag*)(base + 512) = o1;
    }
  }
}

// ---------------- K1: row sums l_i = sum_j exp(S[i,j]) (partial over j-chunk) ----------------
// Double-buffered LDS, 1 barrier/iter, prefetch distance 1.
__global__ __launch_bounds__(256) void k_pass1(
    const short* __restrict__ Kf, const short* __restrict__ Qf,
    float* __restrict__ sumsP) {
  __shared__ int4 ldsQ[2][256];  // 8KB: Q j-tile [kg4][l64] of 16B, x2 buffers
  int ib = blockIdx.x, b = blockIdx.y, jc = blockIdx.z;
  int tid = threadIdx.x, w = tid >> 6, lane = tid & 63;
  int it = ib * 4 + w;
  f32x16 z = zero16();
  bfrag kf[4];
#pragma unroll
  for (int kg = 0; kg < 4; ++kg)
    kf[kg] = *(const bfrag*)&Kf[(((b * 128 + it) * 4 + kg) * 64 + lane) * 8];
  float part[16];
#pragma unroll
  for (int r = 0; r < 16; ++r) part[r] = 0.f;

  int jt0 = jc * 32;
  const int4* q0p = (const int4*)(Qf + (size_t)(b * 128 + jt0) * 2048);
  int4 qc = q0p[tid];
  ldsQ[0][tid] = qc;
  int4 qn = ((const int4*)(Qf + (size_t)(b * 128 + jt0 + 1) * 2048))[tid];
  __syncthreads();

  for (int s = 0; s < 32; ++s) {
    int cur = s & 1;
    bfrag q0 = *(const bfrag*)&ldsQ[cur][0 * 64 + lane];
    bfrag q1 = *(const bfrag*)&ldsQ[cur][1 * 64 + lane];
    bfrag q2 = *(const bfrag*)&ldsQ[cur][2 * 64 + lane];
    bfrag q3 = *(const bfrag*)&ldsQ[cur][3 * 64 + lane];
    f32x16 acc = MFMA(kf[0], q0, z);
    acc = MFMA(kf[1], q1, acc);
    acc = MFMA(kf[2], q2, acc);
    acc = MFMA(kf[3], q3, acc);
#pragma unroll
    for (int r = 0; r < 16; ++r) part[r] += __builtin_amdgcn_exp2f(acc[r]);
    if (s < 31) {
      ldsQ[cur ^ 1][tid] = qn;
      if (s < 30)
        qn = ((const int4*)(Qf + (size_t)(b * 128 + jt0 + s + 2) * 2048))[tid];
      __syncthreads();
    }
  }
#pragma unroll
  for (int r = 0; r < 16; ++r) {
    float v = part[r];
#pragma unroll
    for (int m = 1; m < 32; m <<= 1) v += __shfl_xor(v, m, 64);
    part[r] = v;
  }
  if ((lane & 31) == 0) {
    int h = lane >> 5;
#pragma unroll
    for (int r = 0; r < 16; ++r) {
      int i = it * 32 + (r & 3) + 8 * (r >> 2) + 4 * h;
      sumsP[(b * 4096 + i) * 4 + jc] = part[r];
    }
  }
}

// ---------------- K1b: invl = 1/sum(4 partials) ----------------
__global__ void k_finl(const float* __restrict__ sumsP, float* __restrict__ invl) {
  int idx = blockIdx.x * 256 + threadIdx.x;  // 32768
  const float* s = sumsP + (size_t)idx * 4;
  invl[idx] = 1.0f / (s[0] + s[1] + s[2] + s[3]);
}

// ---------------- K1c: Vf *= invl[i]  (in place; Vf rewritten each call by k_qkv) ----------------
__global__ void k_scalev(short* __restrict__ Vf, const float* __restrict__ invl) {
  int lin = blockIdx.x * 256 + threadIdx.x;  // 262144
  int l = lin & 63, ig = (lin >> 6) & 255, b = lin >> 15;
  short* p = Vf + (size_t)lin * 8;
  bfrag v = *(const bfrag*)p;
  bfrag o;
#pragma unroll
  for (int t = 0; t < 8; ++t) {
    int i = 16 * ig + 4 * (l >> 5) + (t & 3) + 8 * (t >> 2);
    o[t] = f2bf(bf2f(v[t]) * invl[b * 4096 + i]);
  }
  *(bfrag*)p = o;
}

// ---------------- K2: fgs[e,j] = sum_i V'[e,i] * exp(S[i,j]) (partial over i-chunk) ----------------
// Double-buffered LDS, 1 barrier/iter, prefetch distance 1.
__global__ __launch_bounds__(256) void k_pass2(
    const short* __restrict__ Qf, const short* __restrict__ Kf, const short* __restrict__ Vf,
    float* __restrict__ fgsP) {
  __shared__ int4 lds[2][512];  // 16KB: per buffer: K tile (4KB) + V tile (4KB)
  int jb = blockIdx.x, b = blockIdx.y, ic = blockIdx.z;
  int tid = threadIdx.x, w = tid >> 6, lane = tid & 63;
  int jt = jb * 4 + w;
  f32x16 z = zero16();
  bfrag qf[4];
#pragma unroll
  for (int kg = 0; kg < 4; ++kg)
    qf[kg] = *(const bfrag*)&Qf[(((b * 128 + jt) * 4 + kg) * 64 + lane) * 8];
  f32x16 f0 = z, f1 = z;

  int it0 = ic * 32;
  int vh = tid >> 7;        // which e-half (et) this thread stages
  int vtid = tid & 127;
  // prologue: stage tile 0, prefetch tile 1
  int4 kc = ((const int4*)(Kf + (size_t)(b * 128 + it0) * 2048))[tid];
  int4 vc = ((const int4*)(Vf + ((size_t)(b * 2 + vh) * 256 + 2 * it0) * 512))[vtid];
  lds[0][tid] = kc;
  lds[0][256 + tid] = vc;
  int4 kn = ((const int4*)(Kf + (size_t)(b * 128 + it0 + 1) * 2048))[tid];
  int4 vn = ((const int4*)(Vf + ((size_t)(b * 2 + vh) * 256 + 2 * (it0 + 1)) * 512))[vtid];
  __syncthreads();

  for (int s = 0; s < 32; ++s) {
    int cur = s & 1;
    bfrag k0 = *(const bfrag*)&lds[cur][0 * 64 + lane];
    bfrag k1 = *(const bfrag*)&lds[cur][1 * 64 + lane];
    bfrag k2 = *(const bfrag*)&lds[cur][2 * 64 + lane];
    bfrag k3 = *(const bfrag*)&lds[cur][3 * 64 + lane];
    f32x16 sacc = MFMA(k0, qf[0], z);
    sacc = MFMA(k1, qf[1], sacc);
    sacc = MFMA(k2, qf[2], sacc);
    sacc = MFMA(k3, qf[3], sacc);
    bfrag pb0, pb1;  // P frags: regs 0-7 -> i in [0,16), regs 8-15 -> [16,32)
#pragma unroll
    for (int t = 0; t < 8; ++t) {
      pb0[t] = f2bf(__builtin_amdgcn_exp2f(sacc[t]));
      pb1[t] = f2bf(__builtin_amdgcn_exp2f(sacc[t + 8]));
    }
    bfrag v00 = *(const bfrag*)&lds[cur][256 + 0 * 64 + lane];
    bfrag v01 = *(const bfrag*)&lds[cur][256 + 1 * 64 + lane];
    bfrag v10 = *(const bfrag*)&lds[cur][256 + 2 * 64 + lane];
    bfrag v11 = *(const bfrag*)&lds[cur][256 + 3 * 64 + lane];
    f0 = MFMA(v00, pb0, f0);
    f0 = MFMA(v01, pb1, f0);
    f1 = MFMA(v10, pb0, f1);
    f1 = MFMA(v11, pb1, f1);
    if (s < 31) {
      lds[cur ^ 1][tid] = kn;
      lds[cur ^ 1][256 + tid] = vn;
      if (s < 30) {
        kn = ((const int4*)(Kf + (size_t)(b * 128 + it0 + s + 2) * 2048))[tid];
        vn = ((const int4*)(Vf + ((size_t)(b * 2 + vh) * 256 + 2 * (it0 + s + 2)) * 512))[vtid];
      }
      __syncthreads();
    }
  }
  size_t obase = ((size_t)(ic * 8 + b) * 128 + jt) * 4;
#pragma unroll
  for (int h = 0; h < 2; ++h) {
    float* d0 = fgsP + ((obase + 0 + h) * 64 + lane) * 8;
    float* d1 = fgsP + ((obase + 2 + h) * 64 + lane) * 8;
#pragma unroll
    for (int t = 0; t < 8; ++t) {
      d0[t] = f0[8 * h + t];
      d1[t] = f1[8 * h + t];
    }
  }
}

// ---------------- K4: out = w_att @ (sum of fgs partials) + b_att (fp32 out) ----------------
__global__ __launch_bounds__(256) void k_out(
    const float* __restrict__ fgsP, const short* __restrict__ WattF,
    const float* __restrict__ batt, float* __restrict__ out) {
  int jb = blockIdx.x, b = blockIdx.y;
  int tid = threadIdx.x, w = tid >> 6, lane = tid & 63;
  int jt = jb * 4 + w;
  f32x16 z = zero16();
  bfrag gf[4];
#pragma unroll
  for (int kg = 0; kg < 4; ++kg) {
    float s8[8];
#pragma unroll
    for (int t = 0; t < 8; ++t) s8[t] = 0.f;
#pragma unroll
    for (int ic = 0; ic < 4; ++ic) {
      const float* p = fgsP + ((((size_t)ic * 8 + b) * 128 + jt) * 4 + kg) * 512 + lane * 8;
      float4 a0 = *(const float4*)p;
      float4 a1 = *(const float4*)(p + 4);
      s8[0] += a0.x; s8[1] += a0.y; s8[2] += a0.z; s8[3] += a0.w;
      s8[4] += a1.x; s8[5] += a1.y; s8[6] += a1.z; s8[7] += a1.w;
    }
    bfrag g;
#pragma unroll
    for (int t = 0; t < 8; ++t) g[t] = f2bf(s8[t]);
    gf[kg] = g;
  }
  int n = jt * 32 + (lane & 31);
#pragma unroll
  for (int mt = 0; mt < 4; ++mt) {
    bfrag w0 = *(const bfrag*)&WattF[((mt * 4 + 0) * 64 + lane) * 8];
    f32x16 acc = MFMA(w0, gf[0], z);
#pragma unroll
    for (int kg = 1; kg < 4; ++kg) {
      bfrag wf = *(const bfrag*)&WattF[((mt * 4 + kg) * 64 + lane) * 8];
      acc = MFMA(wf, gf[kg], acc);
    }
#pragma unroll
    for (int r = 0; r < 16; ++r) {
      int c = 32 * mt + (r & 3) + 8 * (r >> 2) + 4 * (lane >> 5);
      out[((size_t)(b * 128 + c) << 12) + n] = acc[r] + batt[c];
    }
  }
}

extern "C" void kernel_launch(void* const* d_in, const int* in_sizes, int n_in,
                              void* d_out, int out_size, void* d_ws, size_t ws_size,
                              hipStream_t stream) {
  const float* feat = (const float*)d_in[0];
  const float* wq = (const float*)d_in[1];
  const float* bq = (const float*)d_in[2];
  const float* wk = (const float*)d_in[3];
  const float* bk = (const float*)d_in[4];
  const float* wv = (const float*)d_in[5];
  const float* bv = (const float*)d_in[6];
  const float* watt = (const float*)d_in[7];
  const float* batt = (const float*)d_in[8];
  float* out = (float*)d_out;

  char* ws = (char*)d_ws;
  short* WF = (short*)(ws);
  short* WattF = (short*)(ws + 49152);
  short* Qf = (short*)(ws + 65536);
  short* Kf = (short*)(ws + 65536 + 4194304);
  short* Vf = (short*)(ws + 65536 + 2 * 4194304);
  float* sumsP = (float*)(ws + 65536 + 3 * 4194304);
  float* invl = (float*)(ws + 65536 + 3 * 4194304 + 524288);
  float* fgsP = (float*)(ws + 65536 + 3 * 4194304 + 524288 + 131072);
  // total ws needed: ~46.8 MB

  hipLaunchKernelGGL(k_pack, dim3(128), dim3(256), 0, stream, wq, wk, wv, watt, WF, WattF);
  hipLaunchKernelGGL(k_qkv, dim3(32, 8), dim3(256), 0, stream, feat, WF, bq, bk, bv, Qf, Kf, Vf);
  hipLaunchKernelGGL(k_pass1, dim3(32, 8, 4), dim3(256), 0, stream, Kf, Qf, sumsP);
  hipLaunchKernelGGL(k_finl, dim3(128), dim3(256), 0, stream, sumsP, invl);
  hipLaunchKernelGGL(k_scalev, dim3(1024), dim3(256), 0, stream, Vf, invl);
  hipLaunchKernelGGL(k_pass2, dim3(32, 8, 4), dim3(256), 0, stream, Qf, Kf, Vf, fgsP);
  hipLaunchKernelGGL(k_out, dim3(32, 8), dim3(256), 0, stream, fgsP, WattF, batt, out);
}